// Round 20
// baseline (240.554 us; speedup 1.0000x reference)
//
#include <hip/hip_runtime.h>
#include <math.h>
#include <stdint.h>

#define B_ 8
#define T_ 64
#define S_ 512
#define D_ 512
#define V_ 50000
#define VP_ 50176          // 392 n-tiles of 128
#define M_ (B_*T_)         // 512 rows
#define ROWB_ ((size_t)V_ * 4)   // 200000 bytes per output row slot

typedef __bf16 bf16_t;
typedef bf16_t bf16x8 __attribute__((ext_vector_type(8)));
typedef float  f32x4  __attribute__((ext_vector_type(4)));

// ---------------- reduction helpers (block = 256 threads = 4 waves) ----------------
__device__ inline float blk_sum(float v, float* sm) {
    #pragma unroll
    for (int o = 32; o > 0; o >>= 1) v += __shfl_down(v, o);
    int lane = threadIdx.x & 63, wid = threadIdx.x >> 6;
    __syncthreads();
    if (lane == 0) sm[wid] = v;
    __syncthreads();
    return sm[0] + sm[1] + sm[2] + sm[3];
}

__device__ inline float blk_max(float v, float* sm) {
    #pragma unroll
    for (int o = 32; o > 0; o >>= 1) v = fmaxf(v, __shfl_down(v, o));
    int lane = threadIdx.x & 63, wid = threadIdx.x >> 6;
    __syncthreads();
    if (lane == 0) sm[wid] = v;
    __syncthreads();
    return fmaxf(fmaxf(sm[0], sm[1]), fmaxf(sm[2], sm[3]));
}

__device__ inline void unpack8(uint4 u, float f[8]) {
    uint32_t w0 = u.x, w1 = u.y, w2 = u.z, w3 = u.w;
    f[0] = __uint_as_float(w0 << 16); f[1] = __uint_as_float(w0 & 0xffff0000u);
    f[2] = __uint_as_float(w1 << 16); f[3] = __uint_as_float(w1 & 0xffff0000u);
    f[4] = __uint_as_float(w2 << 16); f[5] = __uint_as_float(w2 & 0xffff0000u);
    f[6] = __uint_as_float(w3 << 16); f[7] = __uint_as_float(w3 & 0xffff0000u);
}

// ---- KPREP: fused small prep. blocks [0,512): k1 per row; [512,520): owner dedupe ----
__global__ __launch_bounds__(256) void kprep(
    const float* __restrict__ x, const float* __restrict__ attn_dist,
    const float* __restrict__ W_pgen, const float* __restrict__ b_pgen,
    float* __restrict__ logalpha_out, float* __restrict__ attn_out, bf16_t* __restrict__ xb,
    const int* __restrict__ idx, int* __restrict__ owner_g)
{
    __shared__ int shb[S_];
    int bid = blockIdx.x;
    int tid = threadIdx.x;

    if (bid < M_) {
        float* sm = reinterpret_cast<float*>(shb);
        int row = bid;

        float2 xv = reinterpret_cast<const float2*>(x + (size_t)row * D_)[tid];
        float2 wv = reinterpret_cast<const float2*>(W_pgen)[tid];
        union { bf16_t h[2]; uint32_t u; } pk;
        pk.h[0] = (bf16_t)xv.x; pk.h[1] = (bf16_t)xv.y;
        reinterpret_cast<uint32_t*>(xb + (size_t)row * D_)[tid] = pk.u;

        float dot = blk_sum(xv.x * wv.x + xv.y * wv.y, sm);
        float alpha = 1.f / (1.f + expf(-(dot + b_pgen[0])));
        if (tid == 0) logalpha_out[row] = logf(alpha);

        float a0 = attn_dist[(size_t)row * S_ + tid];
        float a1 = attn_dist[(size_t)row * S_ + tid + 256];
        float mx = blk_max(fmaxf(a0, a1), sm);
        float e0 = expf(a0 - mx), e1 = expf(a1 - mx);
        float s = blk_sum(e0 + e1, sm);
        float scale = (1.f - alpha) / s;
        attn_out[(size_t)row * S_ + tid]       = e0 * scale;
        attn_out[(size_t)row * S_ + tid + 256] = e1 * scale;
    } else {
        int b = bid - M_;
        for (int s = tid; s < S_; s += 256) shb[s] = idx[b * S_ + s];
        __syncthreads();
        for (int s = tid; s < S_; s += 256) {
            int v = shb[s], o = s;
            for (int s2 = 0; s2 < s; s2++) if (shb[s2] == v) { o = s2; break; }
            owner_g[b * S_ + s] = o;
        }
    }
}

// ---- K2: bf16 MFMA GEMM reading W DIRECTLY (fp32), WRITE-SIDE register transpose.
//  Loads: coalesced (32-lane groups read 512 B of one W row). Each thread owns a
//  4k x 4n block -> cvt bf16 -> 4x ds_write_b64 into Bs[n][slot^((n>>2)&7)] (XOR swz,
//  ~4-way). Fragments: two ds_read_b64 per ni from the same [n][32k] layout the
//  proven Wt-kernel uses (~2-4-way). Grid: 1D XCD-grouped (r18, FETCH 64 MB). ----
#define GBM 128
#define GBN 128
#define GBK 32
#define NTK_ 16

__global__ __launch_bounds__(256) void k2_mfma(
    const bf16_t* __restrict__ A, const float* __restrict__ W,
    const float* __restrict__ bias, char* __restrict__ outB)
{
    __shared__ bf16_t As[2][GBM][GBK];       // 2 x 8 KB
    __shared__ bf16_t Bs[2][GBN * GBK];      // 2 x 8 KB, row n = 32 bf16 = 8 slots of 8 B
    int tid  = threadIdx.x;
    int lane = tid & 63;
    int w    = tid >> 6;             // 0..3
    int wm   = w >> 1, wn = w & 1;   // 2x2 waves, 64x64 each

    // XCD-grouped 1D grid: bn-tile%8 == bid%8 -> 4 bm-sharers of a W panel co-resident
    int bid = blockIdx.x;
    int q = bid >> 5, r = bid & 31;
    int bn = (q * 8 + (r & 7)) * GBN;
    int bm = (r >> 3) * GBM;

    // B staging geometry: kq = tid>>5 (k-quad 0..7), c4w = tid&31 (n-quad 0..31)
    int kq  = tid >> 5;
    int c4w = tid & 31;
    int gv  = bn + c4w * 4;
    bool vok = (gv < V_);

    f32x4 acc[4][4] = {};
    float4 wreg[4];

#define STAGE_A(BUF, K0)                                                               \
    {                                                                                  \
        _Pragma("unroll")                                                              \
        for (int i = 0; i < 2; i++) {                                                  \
            int e = (w * 2 + i) * 512 + lane * 8;                                      \
            int rr_ = e >> 5, c = e & 31;                                              \
            __builtin_amdgcn_global_load_lds(                                          \
                (const __attribute__((address_space(1))) void*)                        \
                    &A[(size_t)(bm + rr_) * D_ + (K0) + c],                            \
                (__attribute__((address_space(3))) void*)&As[BUF][(w * 2 + i) * 16][0],\
                16, 0, 0);                                                             \
        }                                                                              \
    }

    // loads: thread covers k rows kq*4+p (p=0..3), n cols gv..gv+3 (fully coalesced)
#define LOAD_B(K0)                                                                     \
    {                                                                                  \
        _Pragma("unroll")                                                              \
        for (int p = 0; p < 4; p++)                                                    \
            wreg[p] = vok ? *reinterpret_cast<const float4*>(                          \
                                &W[(size_t)((K0) + kq * 4 + p) * V_ + gv])             \
                          : make_float4(0.f, 0.f, 0.f, 0.f);                           \
    }

    // write-side transpose: for each n in the thread's quad, pack its 4 k values
    // (ascending) into one b64 at slot kq ^ ((n>>2)&7) = kq ^ (c4w&7)
#define WRITE_B(BUF)                                                                   \
    {                                                                                  \
        int sl = (kq ^ (c4w & 7)) * 4;                                                 \
        _Pragma("unroll")                                                              \
        for (int j = 0; j < 4; j++) {                                                  \
            int n = c4w * 4 + j;                                                       \
            union { bf16_t h[4]; uint2 u; } pk;                                        \
            pk.h[0] = (bf16_t)(reinterpret_cast<const float*>(&wreg[0])[j]);           \
            pk.h[1] = (bf16_t)(reinterpret_cast<const float*>(&wreg[1])[j]);           \
            pk.h[2] = (bf16_t)(reinterpret_cast<const float*>(&wreg[2])[j]);           \
            pk.h[3] = (bf16_t)(reinterpret_cast<const float*>(&wreg[3])[j]);           \
            *reinterpret_cast<uint2*>(&Bs[BUF][n * GBK + sl]) = pk.u;                  \
        }                                                                              \
    }

#define COMPUTE(BUF)                                                                   \
    {                                                                                  \
        bf16x8 af[4], bfr[4];                                                          \
        int kb = (lane >> 4) * 8;                                                      \
        int s0 = (lane >> 4) * 2;                                                      \
        _Pragma("unroll")                                                              \
        for (int mi = 0; mi < 4; mi++)                                                 \
            af[mi] = *reinterpret_cast<const bf16x8*>(                                 \
                &As[BUF][wm * 64 + mi * 16 + (lane & 15)][kb]);                        \
        _Pragma("unroll")                                                              \
        for (int ni = 0; ni < 4; ni++) {                                               \
            int n = wn * 64 + ni * 16 + (lane & 15);                                   \
            int key = (n >> 2) & 7;                                                    \
            uint2 lo = *reinterpret_cast<const uint2*>(&Bs[BUF][n * GBK + ((s0) ^ key) * 4]);     \
            uint2 hi = *reinterpret_cast<const uint2*>(&Bs[BUF][n * GBK + ((s0 + 1) ^ key) * 4]); \
            union { uint32_t u[4]; bf16x8 v; } uu;                                     \
            uu.u[0] = lo.x; uu.u[1] = lo.y; uu.u[2] = hi.x; uu.u[3] = hi.y;            \
            bfr[ni] = uu.v;                                                            \
        }                                                                              \
        _Pragma("unroll")                                                              \
        for (int mi = 0; mi < 4; mi++)                                                 \
            _Pragma("unroll")                                                          \
            for (int ni = 0; ni < 4; ni++)                                             \
                acc[mi][ni] = __builtin_amdgcn_mfma_f32_16x16x32_bf16(af[mi], bfr[ni], acc[mi][ni], 0, 0, 0); \
    }

    // prologue: tile 0 into buf0
    LOAD_B(0);
    STAGE_A(0, 0);
    asm volatile("s_waitcnt vmcnt(0)" ::: "memory");
    WRITE_B(0);
    __syncthreads();

    #pragma unroll
    for (int tt = 0; tt < NTK_; tt++) {
        int cur = tt & 1, nxt = cur ^ 1;
        if (tt + 1 < NTK_) {
            LOAD_B((tt + 1) * GBK);
            STAGE_A(nxt, (tt + 1) * GBK);
        }
        COMPUTE(cur);
        if (tt + 1 < NTK_) {
            asm volatile("s_waitcnt vmcnt(0)" ::: "memory");
            WRITE_B(nxt);
        }
        __syncthreads();   // drains LDS ops; buffers swap next iteration
    }
#undef STAGE_A
#undef LOAD_B
#undef WRITE_B
#undef COMPUTE

    // epilogue: bf16 logits, row m stored at byte offset m*ROWB_ (first 100352 B of fp32 slot).
    int cm = bm + wm * 64, cn = bn + wn * 64;
    #pragma unroll
    for (int ni = 0; ni < 4; ni++) {
        int n = cn + ni * 16 + (lane & 15);
        float bv = (n < V_) ? bias[n] : 0.f;
        #pragma unroll
        for (int mi = 0; mi < 4; mi++) {
            int rbase = cm + mi * 16 + (lane >> 4) * 4;
            #pragma unroll
            for (int rr = 0; rr < 4; rr++) {
                bf16_t val = (bf16_t)(acc[mi][ni][rr] + bv);
                *reinterpret_cast<bf16_t*>(outB + (size_t)(rbase + rr) * ROWB_ + 2 * (size_t)n) = val;
            }
        }
    }
}

// ---- K345: per-row final: LSE over bf16 row -> logden; in-place descending expand to fp32
//      (out = logit + logalpha - logden); scatter fixup. One block per row.
#define CHUNK_ 2048
#define NCH_ ((V_ + CHUNK_ - 1) / CHUNK_)   // 25

__global__ __launch_bounds__(256) void k345_final(
    char* __restrict__ outB, const float* __restrict__ attn_, const int* __restrict__ idx,
    const int* __restrict__ owner_g, const float* __restrict__ logalpha)
{
    __shared__ float att[S_];
    __shared__ int own[S_], ids[S_];
    __shared__ float smm[4], sms[4];
    int row = blockIdx.x;          // b*T + t
    int b = row >> 6;
    int tid = threadIdx.x;
    int lane = tid & 63, wid = tid >> 6;

    for (int s = tid; s < S_; s += 256) {
        att[s] = attn_[(size_t)row * S_ + s];
        own[s] = owner_g[b * S_ + s];
        ids[s] = idx[b * S_ + s];
    }

    // pass A: online LSE over the bf16 row (V_/8 = 6250 uint4 loads)
    const uint4* L4 = reinterpret_cast<const uint4*>(outB + (size_t)row * ROWB_);
    float m = -INFINITY, se = 0.f;
    for (int i = tid; i < V_ / 8; i += 256) {
        uint4 u = L4[i];
        float f[8]; unpack8(u, f);
        float m8 = fmaxf(fmaxf(fmaxf(f[0], f[1]), fmaxf(f[2], f[3])),
                         fmaxf(fmaxf(f[4], f[5]), fmaxf(f[6], f[7])));
        float mn = fmaxf(m, m8);
        se = se * __expf(m - mn)
           + __expf(f[0] - mn) + __expf(f[1] - mn) + __expf(f[2] - mn) + __expf(f[3] - mn)
           + __expf(f[4] - mn) + __expf(f[5] - mn) + __expf(f[6] - mn) + __expf(f[7] - mn);
        m = mn;
    }
    #pragma unroll
    for (int o = 32; o > 0; o >>= 1) {
        float m2 = __shfl_down(m, o);
        float s2 = __shfl_down(se, o);
        float mn = fmaxf(m, m2);
        if (mn == -INFINITY) { se = 0.f; }
        else se = se * __expf(m - mn) + s2 * __expf(m2 - mn);
        m = mn;
    }
    __syncthreads();               // att/own/ids staged; order smm writes
    if (lane == 0) { smm[wid] = m; sms[wid] = se; }
    __syncthreads();
    float M = smm[0], Ssum = sms[0];
    #pragma unroll
    for (int wv = 1; wv < 4; wv++) {
        float m2 = smm[wv], s2 = sms[wv];
        float mn = fmaxf(M, m2);
        if (mn != -INFINITY) Ssum = Ssum * __expf(M - mn) + s2 * __expf(m2 - mn);
        M = mn;
    }
    float logden = M + logf(Ssum);
    float c_ = logalpha[row] - logden;

    // dedupe-sum attn into owners
    for (int s = tid; s < S_; s += 256)
        if (own[s] != s) atomicAdd(&att[own[s]], att[s]);
    __syncthreads();

    // pass B: in-place expansion bf16 -> fp32, DESCENDING chunks.
    const ushort* Lrow = reinterpret_cast<const ushort*>(outB + (size_t)row * ROWB_);
    float* frow = reinterpret_cast<float*>(outB + (size_t)row * ROWB_);
    for (int c = NCH_ - 1; c >= 0; c--) {
        int i0 = c * CHUNK_ + tid * 8;
        uint4 u = make_uint4(0, 0, 0, 0);
        bool act = (i0 + 8 <= V_);
        if (act) u = *reinterpret_cast<const uint4*>(Lrow + i0);
        __syncthreads();           // all reads of this chunk done before its writes
        if (act) {
            float f[8]; unpack8(u, f);
            float4 lo = make_float4(f[0] + c_, f[1] + c_, f[2] + c_, f[3] + c_);
            float4 hi = make_float4(f[4] + c_, f[5] + c_, f[6] + c_, f[7] + c_);
            *reinterpret_cast<float4*>(frow + i0)     = lo;
            *reinterpret_cast<float4*>(frow + i0 + 4) = hi;
        }
        __syncthreads();           // chunk fully written before next (lower) chunk reads
    }

    // scatter fixup: out[v] = log(exp(out[v]) + att) for owned scattered columns
    for (int s = tid; s < S_; s += 256) {
        if (own[s] == s) {
            int v = ids[s];
            frow[v] = logf(expf(frow[v]) + att[s]);
        }
    }
}

// ================= fallback fp32 path (used only if ws_size too small) =================
__global__ __launch_bounds__(256) void k1_alpha_attn(
    const float* __restrict__ x, const float* __restrict__ attn_dist,
    const float* __restrict__ W_pgen, const float* __restrict__ b_pgen,
    float* __restrict__ logalpha_out, float* __restrict__ attn_out)
{
    __shared__ float sm[4];
    int row = blockIdx.x;
    int tid = threadIdx.x;
    float2 xv = reinterpret_cast<const float2*>(x + (size_t)row * D_)[tid];
    float2 wv = reinterpret_cast<const float2*>(W_pgen)[tid];
    float dot = blk_sum(xv.x * wv.x + xv.y * wv.y, sm);
    float alpha = 1.f / (1.f + expf(-(dot + b_pgen[0])));
    if (tid == 0) logalpha_out[row] = logf(alpha);
    float a0 = attn_dist[(size_t)row * S_ + tid];
    float a1 = attn_dist[(size_t)row * S_ + tid + 256];
    float mx = blk_max(fmaxf(a0, a1), sm);
    float e0 = expf(a0 - mx), e1 = expf(a1 - mx);
    float s = blk_sum(e0 + e1, sm);
    float scale = (1.f - alpha) / s;
    attn_out[(size_t)row * S_ + tid]       = e0 * scale;
    attn_out[(size_t)row * S_ + tid + 256] = e1 * scale;
}

__global__ __launch_bounds__(512) void k5a_owner(const int* __restrict__ idx, int* __restrict__ owner_g)
{
    __shared__ int ids[S_];
    int b = blockIdx.x;
    int s = threadIdx.x;
    ids[s] = idx[b * S_ + s];
    __syncthreads();
    int v = ids[s], o = s;
    for (int s2 = 0; s2 < s; s2++) if (ids[s2] == v) { o = s2; break; }
    owner_g[b * S_ + s] = o;
}

#define BM 64
#define BN 64
#define BK 16
__global__ __launch_bounds__(256) void k2_gemm(
    const float* __restrict__ A, const float* __restrict__ W,
    const float* __restrict__ bias, float* __restrict__ C)
{
    __shared__ float As2[BK][BM + 1];
    __shared__ float Bs2[BK][BN + 1];
    int bn = blockIdx.x * BN;
    int bm = blockIdx.y * BM;
    int tid = threadIdx.x;
    int tx = tid & 15;
    int ty = tid >> 4;
    bool full_n = (bn + BN <= V_);
    float acc[4][4] = {};
    for (int k0 = 0; k0 < D_; k0 += BK) {
        {
            int i = tid * 4;
            int row = i >> 4, col = i & 15;
            const float4 av = *reinterpret_cast<const float4*>(&A[(size_t)(bm + row) * D_ + k0 + col]);
            As2[col + 0][row] = av.x; As2[col + 1][row] = av.y;
            As2[col + 2][row] = av.z; As2[col + 3][row] = av.w;
        }
        {
            int i = tid * 4;
            int row = i >> 6, col = i & 63;
            int gn = bn + col;
            if (full_n) {
                const float4 bv = *reinterpret_cast<const float4*>(&W[(size_t)(k0 + row) * V_ + gn]);
                Bs2[row][col + 0] = bv.x; Bs2[row][col + 1] = bv.y;
                Bs2[row][col + 2] = bv.z; Bs2[row][col + 3] = bv.w;
            } else {
                #pragma unroll
                for (int j = 0; j < 4; j++)
                    Bs2[row][col + j] = (gn + j < V_) ? W[(size_t)(k0 + row) * V_ + gn + j] : 0.f;
            }
        }
        __syncthreads();
        #pragma unroll
        for (int kk = 0; kk < BK; kk++) {
            float a[4], b[4];
            #pragma unroll
            for (int i = 0; i < 4; i++) a[i] = As2[kk][ty * 4 + i];
            #pragma unroll
            for (int j = 0; j < 4; j++) b[j] = Bs2[kk][tx + j * 16];
            #pragma unroll
            for (int i = 0; i < 4; i++)
                #pragma unroll
                for (int j = 0; j < 4; j++)
                    acc[i][j] += a[i] * b[j];
        }
        __syncthreads();
    }
    #pragma unroll
    for (int i = 0; i < 4; i++) {
        int m = bm + ty * 4 + i;
        #pragma unroll
        for (int j = 0; j < 4; j++) {
            int n = bn + tx + j * 16;
            if (n < V_) C[(size_t)m * V_ + n] = acc[i][j] + bias[n];
        }
    }
}

__global__ __launch_bounds__(256) void k3_stats(const float* __restrict__ C, float* __restrict__ logden)
{
    __shared__ float smm[4], sms[4];
    int row = blockIdx.x;
    const float4* p = reinterpret_cast<const float4*>(C + (size_t)row * V_);
    float m = -INFINITY, s = 0.f;
    for (int i = threadIdx.x; i < V_ / 4; i += 256) {
        float4 v = p[i];
        float m4 = fmaxf(fmaxf(v.x, v.y), fmaxf(v.z, v.w));
        if (m4 > m) { s *= expf(m - m4); m = m4; }
        s += expf(v.x - m) + expf(v.y - m) + expf(v.z - m) + expf(v.w - m);
    }
    #pragma unroll
    for (int o = 32; o > 0; o >>= 1) {
        float m2 = __shfl_down(m, o);
        float s2 = __shfl_down(s, o);
        float mn = fmaxf(m, m2);
        s = s * expf(m - mn) + s2 * expf(m2 - mn);
        m = mn;
    }
    int lane = threadIdx.x & 63, wid = threadIdx.x >> 6;
    if (lane == 0) { smm[wid] = m; sms[wid] = s; }
    __syncthreads();
    if (threadIdx.x == 0) {
        float M = smm[0], S = sms[0];
        #pragma unroll
        for (int wv = 1; wv < 4; wv++) {
            float m2 = smm[wv], s2 = sms[wv];
            float mn = fmaxf(M, m2);
            S = S * expf(M - mn) + s2 * expf(m2 - mn);
            M = mn;
        }
        logden[row] = M + logf(S);
    }
}

__global__ __launch_bounds__(256) void k4_scale(
    float* __restrict__ C, const float* __restrict__ logalpha, const float* __restrict__ logden)
{
    int row = blockIdx.y;
    int i = blockIdx.x * 256 + threadIdx.x;
    if (i >= V_ / 4) return;
    float c_ = logalpha[row] - logden[row];
    float4* p = reinterpret_cast<float4*>(C + (size_t)row * V_) + i;
    float4 v = *p;
    v.x += c_; v.y += c_; v.z += c_; v.w += c_;
    *p = v;
}

__global__ __launch_bounds__(256) void k5_scatter_log(
    float* __restrict__ C, const float* __restrict__ attn_, const int* __restrict__ idx,
    const int* __restrict__ owner_g)
{
    __shared__ float att[S_];
    __shared__ int own[S_], ids[S_];
    int row = blockIdx.x;
    int b = row >> 6;
    int tid = threadIdx.x;
    for (int s = tid; s < S_; s += 256) {
        att[s] = attn_[(size_t)row * S_ + s];
        own[s] = owner_g[b * S_ + s];
        ids[s] = idx[b * S_ + s];
    }
    __syncthreads();
    for (int s = tid; s < S_; s += 256)
        if (own[s] != s) atomicAdd(&att[own[s]], att[s]);
    __syncthreads();
    for (int s = tid; s < S_; s += 256) {
        if (own[s] == s) {
            int v = ids[s];
            float* p = &C[(size_t)row * V_ + v];
            *p = logf(expf(*p) + att[s]);
        }
    }
}

// =======================================================================================
extern "C" void kernel_launch(void* const* d_in, const int* in_sizes, int n_in,
                              void* d_out, int out_size, void* d_ws, size_t ws_size,
                              hipStream_t stream) {
    const float* x         = (const float*)d_in[0];   // (B,T,D)
    const float* attn_dist = (const float*)d_in[1];   // (B,T,S)
    const int*   ebev      = (const int*)  d_in[2];   // (B,S)
    const float* W_proj    = (const float*)d_in[3];   // (D,V)
    const float* b_proj    = (const float*)d_in[4];   // (V,)
    const float* W_pgen    = (const float*)d_in[5];   // (D,1)
    const float* b_pgen    = (const float*)d_in[6];   // (1,)
    float* out = (float*)d_out;                       // (B,T,V)
    char*  outB = (char*)d_out;

    // ws layout
    float*  logalpha = (float*)d_ws;                             // 512
    float*  logden   = logalpha + M_;                            // 512 (fallback only)
    float*  attn_    = logden + M_;                              // 262144
    int*    owner    = (int*)(attn_ + (size_t)B_ * T_ * S_);     // 4096
    bf16_t* xb       = (bf16_t*)(owner + (size_t)B_ * S_);       // 262144 bf16
    size_t need = (size_t)(2 * M_ + B_ * T_ * S_ + B_ * S_) * 4
                + (size_t)M_ * D_ * 2;

    if (ws_size >= need) {
        kprep<<<M_ + B_, 256, 0, stream>>>(
            x, attn_dist, W_pgen, b_pgen, logalpha, attn_, xb, ebev, owner);

        k2_mfma<<<(VP_ / GBN) * (M_ / GBM), 256, 0, stream>>>(xb, W_proj, b_proj, outB);

        k345_final<<<M_, 256, 0, stream>>>(outB, attn_, ebev, owner, logalpha);
    } else {
        k1_alpha_attn<<<M_, 256, 0, stream>>>(x, attn_dist, W_pgen, b_pgen, logalpha, attn_);
        k5a_owner<<<B_, 512, 0, stream>>>(ebev, owner);
        dim3 g2((V_ + BN - 1) / BN, M_ / BM);
        k2_gemm<<<g2, 256, 0, stream>>>(x, W_proj, b_proj, out);
        k3_stats<<<M_, 256, 0, stream>>>(out, logden);
        dim3 g4((V_ / 4 + 255) / 256, M_);
        k4_scale<<<g4, 256, 0, stream>>>(out, logalpha, logden);
        k5_scatter_log<<<M_, 256, 0, stream>>>(out, attn_, ebev, owner);
    }
}

// Round 21
// 153.556 us; speedup vs baseline: 1.5666x; 1.5666x over previous
//
#include <hip/hip_runtime.h>
#include <math.h>
#include <stdint.h>

#define B_ 8
#define T_ 64
#define S_ 512
#define D_ 512
#define V_ 50000
#define VP_ 50176          // 392 tiles of 128
#define M_ (B_*T_)         // 512 rows
#define ROWB_ ((size_t)V_ * 4)   // 200000 bytes per output row slot

typedef __bf16 bf16_t;
typedef bf16_t bf16x8 __attribute__((ext_vector_type(8)));
typedef float  f32x4  __attribute__((ext_vector_type(4)));

// ---------------- reduction helpers (block = 256 threads = 4 waves) ----------------
__device__ inline float blk_sum(float v, float* sm) {
    #pragma unroll
    for (int o = 32; o > 0; o >>= 1) v += __shfl_down(v, o);
    int lane = threadIdx.x & 63, wid = threadIdx.x >> 6;
    __syncthreads();
    if (lane == 0) sm[wid] = v;
    __syncthreads();
    return sm[0] + sm[1] + sm[2] + sm[3];
}

__device__ inline float blk_max(float v, float* sm) {
    #pragma unroll
    for (int o = 32; o > 0; o >>= 1) v = fmaxf(v, __shfl_down(v, o));
    int lane = threadIdx.x & 63, wid = threadIdx.x >> 6;
    __syncthreads();
    if (lane == 0) sm[wid] = v;
    __syncthreads();
    return fmaxf(fmaxf(sm[0], sm[1]), fmaxf(sm[2], sm[3]));
}

__device__ inline void unpack8(uint4 u, float f[8]) {
    uint32_t w0 = u.x, w1 = u.y, w2 = u.z, w3 = u.w;
    f[0] = __uint_as_float(w0 << 16); f[1] = __uint_as_float(w0 & 0xffff0000u);
    f[2] = __uint_as_float(w1 << 16); f[3] = __uint_as_float(w1 & 0xffff0000u);
    f[4] = __uint_as_float(w2 << 16); f[5] = __uint_as_float(w2 & 0xffff0000u);
    f[6] = __uint_as_float(w3 << 16); f[7] = __uint_as_float(w3 & 0xffff0000u);
}

// ---- KPREP: fused prep. blocks [0,1568): W transpose (128x128 tiles);
//             [1568,2080): k1; [2080,2088): owner dedupe ----
#define CONVB_ (392 * 4)
#define LTP_ 136   // LDS row pad (bf16 units) for the transpose tile

__global__ __launch_bounds__(256) void kprep(
    const float* __restrict__ W, bf16_t* __restrict__ Wt,
    const float* __restrict__ x, const float* __restrict__ attn_dist,
    const float* __restrict__ W_pgen, const float* __restrict__ b_pgen,
    float* __restrict__ logalpha_out, float* __restrict__ attn_out, bf16_t* __restrict__ xb,
    const int* __restrict__ idx, int* __restrict__ owner_g)
{
    __shared__ bf16_t lt[128 * LTP_];   // 34816 B (conv); aliased by other branches
    int bid = blockIdx.x;
    int tid = threadIdx.x;

    if (bid < CONVB_) {
        // ---- transpose W[D][V] fp32 -> Wt[VP][D] bf16, tile 128k x 128v ----
        // LDS layout: bf16 unit = k*LTP_ + (v ^ (((k>>3)&7)<<2)); bank-clean both phases.
        int vt = bid % 392;                            // v-tile
        int kb = bid / 392;                            // k-band 0..3
        int v0 = vt * 128, k0 = kb * 128;

        // fill: 16 passes, each thread 1 float4 (4 consecutive v of one k-row)
        #pragma unroll
        for (int p = 0; p < 16; p++) {
            int i = p * 256 + tid;       // 0..4095
            int k = i >> 5;              // 0..127
            int c4 = i & 31;             // float4 index in row
            int v = c4 * 4;
            float4 val = make_float4(0.f, 0.f, 0.f, 0.f);
            if (v0 + v < V_)             // V_ % 4 == 0 -> full float4 in-bounds
                val = *reinterpret_cast<const float4*>(&W[(size_t)(k0 + k) * V_ + v0 + v]);
            int key = (k >> 3) & 7;
            union { bf16_t h[4]; uint2 u; } pk;
            pk.h[0] = (bf16_t)val.x; pk.h[1] = (bf16_t)val.y;
            pk.h[2] = (bf16_t)val.z; pk.h[3] = (bf16_t)val.w;
            *reinterpret_cast<uint2*>(&lt[k * LTP_ + ((c4 ^ key) << 2)]) = pk.u;
        }
        __syncthreads();

        // drain: 8 passes, each thread packs 8 k (one 16-B chunk of a Wt row)
        #pragma unroll
        for (int p = 0; p < 8; p++) {
            int i = p * 256 + tid;       // 0..2047
            int v = i >> 4;              // 0..127
            int kc = (i & 15) * 8;       // 0..120
            int key = (kc >> 3) & 7;     // = i & 7
            union { ushort h[8]; uint4 u; } pk;
            #pragma unroll
            for (int j = 0; j < 8; j++)
                pk.h[j] = *reinterpret_cast<const ushort*>(
                    &lt[(kc + j) * LTP_ + (v ^ (key << 2))]);
            *reinterpret_cast<uint4*>(&Wt[(size_t)(v0 + v) * D_ + k0 + kc]) = pk.u;
        }
    } else if (bid < CONVB_ + M_) {
        // ---- k1: alpha/logalpha, attn_ = (1-alpha)*softmax(attn_dist), xb = bf16(x) ----
        float* sm = reinterpret_cast<float*>(lt);
        int row = bid - CONVB_;

        float2 xv = reinterpret_cast<const float2*>(x + (size_t)row * D_)[tid];
        float2 wv = reinterpret_cast<const float2*>(W_pgen)[tid];
        union { bf16_t h[2]; uint32_t u; } pk;
        pk.h[0] = (bf16_t)xv.x; pk.h[1] = (bf16_t)xv.y;
        reinterpret_cast<uint32_t*>(xb + (size_t)row * D_)[tid] = pk.u;

        float dot = blk_sum(xv.x * wv.x + xv.y * wv.y, sm);
        float alpha = 1.f / (1.f + expf(-(dot + b_pgen[0])));
        if (tid == 0) logalpha_out[row] = logf(alpha);

        float a0 = attn_dist[(size_t)row * S_ + tid];
        float a1 = attn_dist[(size_t)row * S_ + tid + 256];
        float mx = blk_max(fmaxf(a0, a1), sm);
        float e0 = expf(a0 - mx), e1 = expf(a1 - mx);
        float s = blk_sum(e0 + e1, sm);
        float scale = (1.f - alpha) / s;
        attn_out[(size_t)row * S_ + tid]       = e0 * scale;
        attn_out[(size_t)row * S_ + tid + 256] = e1 * scale;
    } else {
        // ---- k5a: per-batch dedupe owner[s] = first s' with same index ----
        int* ids = reinterpret_cast<int*>(lt);
        int b = bid - (CONVB_ + M_);
        for (int s = tid; s < S_; s += 256) ids[s] = idx[b * S_ + s];
        __syncthreads();
        for (int s = tid; s < S_; s += 256) {
            int v = ids[s], o = s;
            for (int s2 = 0; s2 < s; s2++) if (ids[s2] == v) { o = s2; break; }
            owner_g[b * S_ + s] = o;
        }
    }
}

// ---- K2: bf16 MFMA GEMM — double-buffer core + bf16 in-place epilogue ----
#define GBM 128
#define GBN 128
#define GBK 32
#define NT2_ (D_/GBK)    // 16

__global__ __launch_bounds__(256) void k2_mfma(
    const bf16_t* __restrict__ A, const bf16_t* __restrict__ Wt,
    const float* __restrict__ bias, char* __restrict__ outB)
{
    __shared__ bf16_t As0[GBM][GBK], As1[GBM][GBK];   // 8 KB each
    __shared__ bf16_t Bs0[GBN][GBK], Bs1[GBN][GBK];
    int tid  = threadIdx.x;
    int lane = tid & 63;
    int w    = tid >> 6;             // 0..3
    int wm   = w >> 1, wn = w & 1;   // 2x2 waves, 64x64 each
    int bn = blockIdx.x * GBN;       // 2D grid: XCD = bid%8 = bn-tile%8 (392%8==0)
    int bm = blockIdx.y * GBM;

    f32x4 acc[4][4] = {};

#define STAGE(dstA, dstB, k0)                                                          \
    {                                                                                  \
        _Pragma("unroll")                                                              \
        for (int i = 0; i < 2; i++) {                                                  \
            int e = (w * 2 + i) * 512 + lane * 8;                                      \
            int r = e >> 5, c = e & 31;                                                \
            __builtin_amdgcn_global_load_lds(                                          \
                (const __attribute__((address_space(1))) void*)                        \
                    &A[(size_t)(bm + r) * D_ + (k0) + c],                              \
                (__attribute__((address_space(3))) void*)&dstA[(w * 2 + i) * 16][0],   \
                16, 0, 0);                                                             \
            __builtin_amdgcn_global_load_lds(                                          \
                (const __attribute__((address_space(1))) void*)                        \
                    &Wt[(size_t)(bn + r) * D_ + (k0) + c],                             \
                (__attribute__((address_space(3))) void*)&dstB[(w * 2 + i) * 16][0],   \
                16, 0, 0);                                                             \
        }                                                                              \
    }

#define COMPUTE(srcA, srcB)                                                            \
    {                                                                                  \
        bf16x8 af[4], bfr[4];                                                          \
        int kb = (lane >> 4) * 8;                                                      \
        _Pragma("unroll")                                                              \
        for (int mi = 0; mi < 4; mi++)                                                 \
            af[mi] = *reinterpret_cast<const bf16x8*>(&srcA[wm * 64 + mi * 16 + (lane & 15)][kb]); \
        _Pragma("unroll")                                                              \
        for (int ni = 0; ni < 4; ni++)                                                 \
            bfr[ni] = *reinterpret_cast<const bf16x8*>(&srcB[wn * 64 + ni * 16 + (lane & 15)][kb]); \
        _Pragma("unroll")                                                              \
        for (int mi = 0; mi < 4; mi++)                                                 \
            _Pragma("unroll")                                                          \
            for (int ni = 0; ni < 4; ni++)                                             \
                acc[mi][ni] = __builtin_amdgcn_mfma_f32_16x16x32_bf16(af[mi], bfr[ni], acc[mi][ni], 0, 0, 0); \
    }

    // prologue: stage tile 0 into buf0
    STAGE(As0, Bs0, 0);
    asm volatile("s_waitcnt vmcnt(0)" ::: "memory");
    __syncthreads();

    #pragma unroll
    for (int tt = 0; tt < NT2_ / 2; tt++) {
        int k0 = tt * 2 * GBK;
        if (k0 + GBK < D_) STAGE(As1, Bs1, k0 + GBK);
        COMPUTE(As0, Bs0);
        asm volatile("s_waitcnt vmcnt(0)" ::: "memory");
        __syncthreads();
        if (k0 + 2 * GBK < D_) STAGE(As0, Bs0, k0 + 2 * GBK);
        COMPUTE(As1, Bs1);
        asm volatile("s_waitcnt vmcnt(0)" ::: "memory");
        __syncthreads();
    }
#undef STAGE
#undef COMPUTE

    // epilogue: bf16 logits, row m stored at byte offset m*ROWB_ (first 100352 B of fp32 slot).
    int cm = bm + wm * 64, cn = bn + wn * 64;
    #pragma unroll
    for (int ni = 0; ni < 4; ni++) {
        int n = cn + ni * 16 + (lane & 15);
        float bv = (n < V_) ? bias[n] : 0.f;
        #pragma unroll
        for (int mi = 0; mi < 4; mi++) {
            int rbase = cm + mi * 16 + (lane >> 4) * 4;
            #pragma unroll
            for (int r = 0; r < 4; r++) {
                bf16_t val = (bf16_t)(acc[mi][ni][r] + bv);
                *reinterpret_cast<bf16_t*>(outB + (size_t)(rbase + r) * ROWB_ + 2 * (size_t)n) = val;
            }
        }
    }
}

// ---- K345: per-row final: LSE over bf16 row -> logden; in-place descending expand to fp32
//      (out = logit + logalpha - logden); scatter fixup. One block per row.
#define CHUNK_ 2048
#define NCH_ ((V_ + CHUNK_ - 1) / CHUNK_)   // 25

__global__ __launch_bounds__(256) void k345_final(
    char* __restrict__ outB, const float* __restrict__ attn_, const int* __restrict__ idx,
    const int* __restrict__ owner_g, const float* __restrict__ logalpha)
{
    __shared__ float att[S_];
    __shared__ int own[S_], ids[S_];
    __shared__ float smm[4], sms[4];
    int row = blockIdx.x;          // b*T + t
    int b = row >> 6;
    int tid = threadIdx.x;
    int lane = tid & 63, wid = tid >> 6;

    for (int s = tid; s < S_; s += 256) {
        att[s] = attn_[(size_t)row * S_ + s];
        own[s] = owner_g[b * S_ + s];
        ids[s] = idx[b * S_ + s];
    }

    // pass A: online LSE over the bf16 row (V_/8 = 6250 uint4 loads)
    const uint4* L4 = reinterpret_cast<const uint4*>(outB + (size_t)row * ROWB_);
    float m = -INFINITY, se = 0.f;
    for (int i = tid; i < V_ / 8; i += 256) {
        uint4 u = L4[i];
        float f[8]; unpack8(u, f);
        float m8 = fmaxf(fmaxf(fmaxf(f[0], f[1]), fmaxf(f[2], f[3])),
                         fmaxf(fmaxf(f[4], f[5]), fmaxf(f[6], f[7])));
        float mn = fmaxf(m, m8);
        se = se * __expf(m - mn)
           + __expf(f[0] - mn) + __expf(f[1] - mn) + __expf(f[2] - mn) + __expf(f[3] - mn)
           + __expf(f[4] - mn) + __expf(f[5] - mn) + __expf(f[6] - mn) + __expf(f[7] - mn);
        m = mn;
    }
    #pragma unroll
    for (int o = 32; o > 0; o >>= 1) {
        float m2 = __shfl_down(m, o);
        float s2 = __shfl_down(se, o);
        float mn = fmaxf(m, m2);
        if (mn == -INFINITY) { se = 0.f; }
        else se = se * __expf(m - mn) + s2 * __expf(m2 - mn);
        m = mn;
    }
    __syncthreads();               // att/own/ids staged; order smm writes
    if (lane == 0) { smm[wid] = m; sms[wid] = se; }
    __syncthreads();
    float M = smm[0], Ssum = sms[0];
    #pragma unroll
    for (int wv = 1; wv < 4; wv++) {
        float m2 = smm[wv], s2 = sms[wv];
        float mn = fmaxf(M, m2);
        if (mn != -INFINITY) Ssum = Ssum * __expf(M - mn) + s2 * __expf(m2 - mn);
        M = mn;
    }
    float logden = M + logf(Ssum);
    float c_ = logalpha[row] - logden;

    // dedupe-sum attn into owners
    for (int s = tid; s < S_; s += 256)
        if (own[s] != s) atomicAdd(&att[own[s]], att[s]);
    __syncthreads();

    // pass B: in-place expansion bf16 -> fp32, DESCENDING chunks.
    const ushort* Lrow = reinterpret_cast<const ushort*>(outB + (size_t)row * ROWB_);
    float* frow = reinterpret_cast<float*>(outB + (size_t)row * ROWB_);
    for (int c = NCH_ - 1; c >= 0; c--) {
        int i0 = c * CHUNK_ + tid * 8;
        uint4 u = make_uint4(0, 0, 0, 0);
        bool act = (i0 + 8 <= V_);
        if (act) u = *reinterpret_cast<const uint4*>(Lrow + i0);
        __syncthreads();           // all reads of this chunk done before its writes
        if (act) {
            float f[8]; unpack8(u, f);
            float4 lo = make_float4(f[0] + c_, f[1] + c_, f[2] + c_, f[3] + c_);
            float4 hi = make_float4(f[4] + c_, f[5] + c_, f[6] + c_, f[7] + c_);
            *reinterpret_cast<float4*>(frow + i0)     = lo;
            *reinterpret_cast<float4*>(frow + i0 + 4) = hi;
        }
        __syncthreads();           // chunk fully written before next (lower) chunk reads
    }

    // scatter fixup: out[v] = log(exp(out[v]) + att) for owned scattered columns
    for (int s = tid; s < S_; s += 256) {
        if (own[s] == s) {
            int v = ids[s];
            frow[v] = logf(expf(frow[v]) + att[s]);
        }
    }
}

// ================= fallback fp32 path (used only if ws_size too small) =================
__global__ __launch_bounds__(256) void k1_alpha_attn(
    const float* __restrict__ x, const float* __restrict__ attn_dist,
    const float* __restrict__ W_pgen, const float* __restrict__ b_pgen,
    float* __restrict__ logalpha_out, float* __restrict__ attn_out)
{
    __shared__ float sm[4];
    int row = blockIdx.x;
    int tid = threadIdx.x;
    float2 xv = reinterpret_cast<const float2*>(x + (size_t)row * D_)[tid];
    float2 wv = reinterpret_cast<const float2*>(W_pgen)[tid];
    float dot = blk_sum(xv.x * wv.x + xv.y * wv.y, sm);
    float alpha = 1.f / (1.f + expf(-(dot + b_pgen[0])));
    if (tid == 0) logalpha_out[row] = logf(alpha);
    float a0 = attn_dist[(size_t)row * S_ + tid];
    float a1 = attn_dist[(size_t)row * S_ + tid + 256];
    float mx = blk_max(fmaxf(a0, a1), sm);
    float e0 = expf(a0 - mx), e1 = expf(a1 - mx);
    float s = blk_sum(e0 + e1, sm);
    float scale = (1.f - alpha) / s;
    attn_out[(size_t)row * S_ + tid]       = e0 * scale;
    attn_out[(size_t)row * S_ + tid + 256] = e1 * scale;
}

__global__ __launch_bounds__(512) void k5a_owner(const int* __restrict__ idx, int* __restrict__ owner_g)
{
    __shared__ int ids[S_];
    int b = blockIdx.x;
    int s = threadIdx.x;
    ids[s] = idx[b * S_ + s];
    __syncthreads();
    int v = ids[s], o = s;
    for (int s2 = 0; s2 < s; s2++) if (ids[s2] == v) { o = s2; break; }
    owner_g[b * S_ + s] = o;
}

#define BM 64
#define BN 64
#define BK 16
__global__ __launch_bounds__(256) void k2_gemm(
    const float* __restrict__ A, const float* __restrict__ W,
    const float* __restrict__ bias, float* __restrict__ C)
{
    __shared__ float As2[BK][BM + 1];
    __shared__ float Bs2[BK][BN + 1];
    int bn = blockIdx.x * BN;
    int bm = blockIdx.y * BM;
    int tid = threadIdx.x;
    int tx = tid & 15;
    int ty = tid >> 4;
    bool full_n = (bn + BN <= V_);
    float acc[4][4] = {};
    for (int k0 = 0; k0 < D_; k0 += BK) {
        {
            int i = tid * 4;
            int row = i >> 4, col = i & 15;
            const float4 av = *reinterpret_cast<const float4*>(&A[(size_t)(bm + row) * D_ + k0 + col]);
            As2[col + 0][row] = av.x; As2[col + 1][row] = av.y;
            As2[col + 2][row] = av.z; As2[col + 3][row] = av.w;
        }
        {
            int i = tid * 4;
            int row = i >> 6, col = i & 63;
            int gn = bn + col;
            if (full_n) {
                const float4 bv = *reinterpret_cast<const float4*>(&W[(size_t)(k0 + row) * V_ + gn]);
                Bs2[row][col + 0] = bv.x; Bs2[row][col + 1] = bv.y;
                Bs2[row][col + 2] = bv.z; Bs2[row][col + 3] = bv.w;
            } else {
                #pragma unroll
                for (int j = 0; j < 4; j++)
                    Bs2[row][col + j] = (gn + j < V_) ? W[(size_t)(k0 + row) * V_ + gn + j] : 0.f;
            }
        }
        __syncthreads();
        #pragma unroll
        for (int kk = 0; kk < BK; kk++) {
            float a[4], b[4];
            #pragma unroll
            for (int i = 0; i < 4; i++) a[i] = As2[kk][ty * 4 + i];
            #pragma unroll
            for (int j = 0; j < 4; j++) b[j] = Bs2[kk][tx + j * 16];
            #pragma unroll
            for (int i = 0; i < 4; i++)
                #pragma unroll
                for (int j = 0; j < 4; j++)
                    acc[i][j] += a[i] * b[j];
        }
        __syncthreads();
    }
    #pragma unroll
    for (int i = 0; i < 4; i++) {
        int m = bm + ty * 4 + i;
        #pragma unroll
        for (int j = 0; j < 4; j++) {
            int n = bn + tx + j * 16;
            if (n < V_) C[(size_t)m * V_ + n] = acc[i][j] + bias[n];
        }
    }
}

__global__ __launch_bounds__(256) void k3_stats(const float* __restrict__ C, float* __restrict__ logden)
{
    __shared__ float smm[4], sms[4];
    int row = blockIdx.x;
    const float4* p = reinterpret_cast<const float4*>(C + (size_t)row * V_);
    float m = -INFINITY, s = 0.f;
    for (int i = threadIdx.x; i < V_ / 4; i += 256) {
        float4 v = p[i];
        float m4 = fmaxf(fmaxf(v.x, v.y), fmaxf(v.z, v.w));
        if (m4 > m) { s *= expf(m - m4); m = m4; }
        s += expf(v.x - m) + expf(v.y - m) + expf(v.z - m) + expf(v.w - m);
    }
    #pragma unroll
    for (int o = 32; o > 0; o >>= 1) {
        float m2 = __shfl_down(m, o);
        float s2 = __shfl_down(s, o);
        float mn = fmaxf(m, m2);
        s = s * expf(m - mn) + s2 * expf(m2 - mn);
        m = mn;
    }
    int lane = threadIdx.x & 63, wid = threadIdx.x >> 6;
    if (lane == 0) { smm[wid] = m; sms[wid] = s; }
    __syncthreads();
    if (threadIdx.x == 0) {
        float M = smm[0], S = sms[0];
        #pragma unroll
        for (int wv = 1; wv < 4; wv++) {
            float m2 = smm[wv], s2 = sms[wv];
            float mn = fmaxf(M, m2);
            S = S * expf(M - mn) + s2 * expf(m2 - mn);
            M = mn;
        }
        logden[row] = M + logf(S);
    }
}

__global__ __launch_bounds__(256) void k4_scale(
    float* __restrict__ C, const float* __restrict__ logalpha, const float* __restrict__ logden)
{
    int row = blockIdx.y;
    int i = blockIdx.x * 256 + threadIdx.x;
    if (i >= V_ / 4) return;
    float c_ = logalpha[row] - logden[row];
    float4* p = reinterpret_cast<float4*>(C + (size_t)row * V_) + i;
    float4 v = *p;
    v.x += c_; v.y += c_; v.z += c_; v.w += c_;
    *p = v;
}

__global__ __launch_bounds__(256) void k5_scatter_log(
    float* __restrict__ C, const float* __restrict__ attn_, const int* __restrict__ idx,
    const int* __restrict__ owner_g)
{
    __shared__ float att[S_];
    __shared__ int own[S_], ids[S_];
    int row = blockIdx.x;
    int b = row >> 6;
    int tid = threadIdx.x;
    for (int s = tid; s < S_; s += 256) {
        att[s] = attn_[(size_t)row * S_ + s];
        own[s] = owner_g[b * S_ + s];
        ids[s] = idx[b * S_ + s];
    }
    __syncthreads();
    for (int s = tid; s < S_; s += 256)
        if (own[s] != s) atomicAdd(&att[own[s]], att[s]);
    __syncthreads();
    for (int s = tid; s < S_; s += 256) {
        if (own[s] == s) {
            int v = ids[s];
            float* p = &C[(size_t)row * V_ + v];
            *p = logf(expf(*p) + att[s]);
        }
    }
}

// =======================================================================================
extern "C" void kernel_launch(void* const* d_in, const int* in_sizes, int n_in,
                              void* d_out, int out_size, void* d_ws, size_t ws_size,
                              hipStream_t stream) {
    const float* x         = (const float*)d_in[0];   // (B,T,D)
    const float* attn_dist = (const float*)d_in[1];   // (B,T,S)
    const int*   ebev      = (const int*)  d_in[2];   // (B,S)
    const float* W_proj    = (const float*)d_in[3];   // (D,V)
    const float* b_proj    = (const float*)d_in[4];   // (V,)
    const float* W_pgen    = (const float*)d_in[5];   // (D,1)
    const float* b_pgen    = (const float*)d_in[6];   // (1,)
    float* out = (float*)d_out;                       // (B,T,V)
    char*  outB = (char*)d_out;

    // ws layout
    float*  logalpha = (float*)d_ws;                             // 512
    float*  logden   = logalpha + M_;                            // 512 (fallback only)
    float*  attn_    = logden + M_;                              // 262144
    int*    owner    = (int*)(attn_ + (size_t)B_ * T_ * S_);     // 4096
    bf16_t* xb       = (bf16_t*)(owner + (size_t)B_ * S_);       // 262144 bf16
    bf16_t* Wt       = xb + (size_t)M_ * D_;
    size_t need = (size_t)(2 * M_ + B_ * T_ * S_ + B_ * S_) * 4
                + (size_t)M_ * D_ * 2 + (size_t)VP_ * D_ * 2;

    if (ws_size >= need) {
        kprep<<<CONVB_ + M_ + B_, 256, 0, stream>>>(
            W_proj, Wt, x, attn_dist, W_pgen, b_pgen, logalpha, attn_, xb, ebev, owner);

        dim3 g2(VP_ / GBN, M_ / GBM);   // 2D grid: XCD = bid%8 = bn-tile%8 (392 % 8 == 0)
        k2_mfma<<<g2, 256, 0, stream>>>(xb, Wt, b_proj, outB);

        k345_final<<<M_, 256, 0, stream>>>(outB, attn_, ebev, owner, logalpha);
    } else {
        k1_alpha_attn<<<M_, 256, 0, stream>>>(x, attn_dist, W_pgen, b_pgen, logalpha, attn_);
        k5a_owner<<<B_, 512, 0, stream>>>(ebev, owner);
        dim3 g2((V_ + BN - 1) / BN, M_ / BM);
        k2_gemm<<<g2, 256, 0, stream>>>(x, W_proj, b_proj, out);
        k3_stats<<<M_, 256, 0, stream>>>(out, logden);
        dim3 g4((V_ / 4 + 255) / 256, M_);
        k4_scale<<<g4, 256, 0, stream>>>(out, logalpha, logden);
        k5_scatter_log<<<M_, 256, 0, stream>>>(out, attn_, ebev, owner);
    }
}